// Round 2
// baseline (270.037 us; speedup 1.0000x reference)
//
#include <hip/hip_runtime.h>
#include <hip/hip_fp16.h>
#include <stdint.h>
#include <string.h>

#define NV 40962     // vertices
#define NC 64        // in channels
#define NO 64        // out channels
#define NM 27        // neighbors*3
#define NB 4         // batch
#define KP 576       // K = 9*64, permuted t = k*64 + c (k-major)
#define NPAD 28      // padded pairs per vertex (112 B rows, 16B-aligned)

using fragh = __attribute__((ext_vector_type(8))) _Float16;  // 8 f16 (4 VGPRs)
using f32x4 = __attribute__((ext_vector_type(4))) float;     // MFMA acc

__device__ inline __half2 uh2(unsigned int u) { __half2 h; memcpy(&h, &u, 4); return h; }
__device__ inline unsigned int h2u(__half2 h) { unsigned int u; memcpy(&u, &h, 4); return u; }
__device__ inline unsigned short f2h(float f) {
    __half h = __float2half_rn(f);
    unsigned short u; memcpy(&u, &h, 2); return u;
}
__device__ inline unsigned int pack_h2(float a, float b) {
    __half2 h = __floats2half2_rn(a, b);
    unsigned int u; memcpy(&u, &h, 4); return u;
}
__device__ inline unsigned int comp(const uint4& v, int i) {
    switch (i & 3) { case 0: return v.x; case 1: return v.y; case 2: return v.z; default: return v.w; }
}

// ---- prep: W -> Wp f16 (t = k*64+c), and (idx,w) -> packed pairs (f16 w | idx) ----
__global__ __launch_bounds__(256) void prep_kernel(const float* __restrict__ W,
                                                   const int* __restrict__ nidx,
                                                   const float* __restrict__ nwt,
                                                   unsigned short* __restrict__ Wp,
                                                   unsigned int* __restrict__ pairs) {
    int i = blockIdx.x * 256 + threadIdx.x;
    if (i < NO * KP) {
        int o = i / KP, t = i % KP;
        int k = t >> 6, c = t & 63;
        Wp[i] = f2h(W[o * 576 + c * 9 + k]);
    }
    if (i < NV * NPAD) {
        int v = i / NPAD, j = i - v * NPAD;
        unsigned int pv = 0;
        if (j < NM) {
            unsigned int id = (unsigned int)nidx[v * NM + j];   // < 40962, fits 16 bits
            unsigned int wb = (unsigned int)f2h(nwt[v * NM + j]);
            pv = (wb << 16) | (id & 0xffffu);
        }
        pairs[i] = pv;
    }
}

// ---- x (B,C,V) fp32 -> xt (B,V,C) f16 ----
__global__ __launch_bounds__(256) void transpose_kernel(const float* __restrict__ x,
                                                        unsigned short* __restrict__ xt) {
    __shared__ float tile[64][65];
    int b = blockIdx.y;
    int v0 = blockIdx.x * 64;
    int t = threadIdx.x;
    int tv = t & 63, tc = t >> 6;
    const float* xb = x + (size_t)b * NC * NV;
    #pragma unroll
    for (int i = 0; i < 16; i++) {
        int c = tc + i * 4;
        int v = v0 + tv;
        tile[c][tv] = (v < NV) ? xb[(size_t)c * NV + v] : 0.f;
    }
    __syncthreads();
    unsigned short* xtb = xt + (size_t)b * NV * NC;
    #pragma unroll
    for (int i = 0; i < 2; i++) {
        int r = i * 32 + (t >> 3);
        int ch0 = (t & 7) * 8;
        int v = v0 + r;
        if (v < NV) {
            unsigned int o[4];
            #pragma unroll
            for (int j = 0; j < 4; j++)
                o[j] = pack_h2(tile[ch0 + 2 * j][r], tile[ch0 + 2 * j + 1][r]);
            *(uint4*)(xtb + (size_t)v * NC + ch0) = *(const uint4*)o;
        }
    }
}

// ---- fused gather + MFMA GEMM, zero LDS ----
// block = 256 = 4 waves; wave w handles BATCH w for the block's 16-vertex tile.
// Per wave: 16 vertices x 64 outputs x 1 batch.
// lane = (q = lane>>4, m = lane&15). Lane's gathered channels q*8..+7 (lo)
// and 32+q*8..+7 (hi) ARE the A-frag layout for k-steps 2k / 2k+1.
// Per k-slot: 6 gathers (3 neighbors x 2 halves), 24 pk_fma_f16, 8 MFMAs.
// 1-slot gather lookahead (only 12 uint4 of in-flight state per wave, so the
// register allocator can actually keep the lookahead loads hoisted).
// All 4 waves share pairs rows + Wp B-frag addresses -> L1 hits.
__global__ __launch_bounds__(256, 4) void fused_kernel(
    const unsigned short* __restrict__ xt,
    const unsigned int* __restrict__ pairs,
    const unsigned short* __restrict__ Wp,
    const float* __restrict__ bias,
    float* __restrict__ out)
{
    int lane = threadIdx.x & 63;
    int w = threadIdx.x >> 6;   // wave id == batch index
    int q = lane >> 4;          // channel quad
    int m = lane & 15;          // vertex within tile
    int n0 = blockIdx.x * 16;
    int vtx = n0 + m; if (vtx >= NV) vtx = NV - 1;
    const char* xb = (const char*)xt + (size_t)w * NV * NC * 2;
    int cofs = q * 16;

    // all 27 (idx | f16 w) pairs for this lane's vertex
    uint4 pr[7];
    {
        const uint4* pp = (const uint4*)(pairs + (size_t)vtx * NPAD);
        #pragma unroll
        for (int j = 0; j < 7; j++) pr[j] = pp[j];
    }

    f32x4 c[4];
    #pragma unroll
    for (int j = 0; j < 4; j++) c[j] = (f32x4){0.f, 0.f, 0.f, 0.f};

    uint4 ga[2][3], gb[2][3];  // [buf][neighbor]

    // prologue: issue k-slot 0 gathers
    #pragma unroll
    for (int j = 0; j < 3; j++) {
        unsigned int pm = comp(pr[0], j);
        unsigned int off = ((pm & 0xffffu) << 7) + cofs;
        ga[0][j] = *(const uint4*)(xb + off);
        gb[0][j] = *(const uint4*)(xb + off + 64);
    }

    const unsigned short* wrow = Wp + q * 8;

    #pragma unroll
    for (int k = 0; k < 9; k++) {
        int cur = k & 1, nxt = cur ^ 1;
        // lookahead: issue k+1's 6 gathers before consuming k's
        if (k < 8) {
            #pragma unroll
            for (int j = 0; j < 3; j++) {
                int mm = 3 * (k + 1) + j;
                unsigned int pm = comp(pr[mm >> 2], mm);
                unsigned int off = ((pm & 0xffffu) << 7) + cofs;
                ga[nxt][j] = *(const uint4*)(xb + off);
                gb[nxt][j] = *(const uint4*)(xb + off + 64);
            }
        }
        // accumulate k's 3 neighbors, 16 channels — packed f16 fma
        unsigned int accA[4] = {0u, 0u, 0u, 0u};
        unsigned int accB[4] = {0u, 0u, 0u, 0u};
        #pragma unroll
        for (int j = 0; j < 3; j++) {
            int mm = 3 * k + j;
            unsigned int pm = comp(pr[mm >> 2], mm);
            unsigned int wh = pm >> 16;
            __half2 w2 = uh2((wh << 16) | wh);
            uint4 u0 = ga[cur][j];
            uint4 u1 = gb[cur][j];
            const unsigned int d0[4] = {u0.x, u0.y, u0.z, u0.w};
            const unsigned int d1[4] = {u1.x, u1.y, u1.z, u1.w};
            #pragma unroll
            for (int d = 0; d < 4; d++) {
                accA[d] = h2u(__hfma2(uh2(d0[d]), w2, uh2(accA[d])));
                accB[d] = h2u(__hfma2(uh2(d1[d]), w2, uh2(accB[d])));
            }
        }
        // acc registers ARE the A-frags; run k-steps 2k (lo) and 2k+1 (hi)
        fragh a0, a1;
        memcpy(&a0, accA, 16);
        memcpy(&a1, accB, 16);
        #pragma unroll
        for (int j = 0; j < 4; j++) {
            fragh blo = *(const fragh*)(wrow + (size_t)(j * 16 + m) * KP + (2 * k) * 32);
            fragh bhi = *(const fragh*)(wrow + (size_t)(j * 16 + m) * KP + (2 * k + 1) * 32);
            c[j] = __builtin_amdgcn_mfma_f32_16x16x32_f16(a0, blo, c[j], 0, 0, 0);
            c[j] = __builtin_amdgcn_mfma_f32_16x16x32_f16(a1, bhi, c[j], 0, 0, 0);
        }
    }

    // epilogue: D[row = q*4+i (vertex)][col = m+16j (out)], + bias, float2 stores
    int nbase = n0 + q * 4;
    size_t outb = (size_t)w * NO * NV;
    #pragma unroll
    for (int j = 0; j < 4; j++) {
        int o = j * 16 + m;
        float bo = bias[o];
        f32x4 vv = c[j];
        float* op = out + outb + (size_t)o * NV + nbase;
        if (nbase + 4 <= NV) {
            *(float2*)op       = make_float2(vv[0] + bo, vv[1] + bo);
            *(float2*)(op + 2) = make_float2(vv[2] + bo, vv[3] + bo);
        } else {
            #pragma unroll
            for (int i = 0; i < 4; i++)
                if (nbase + i < NV) op[i] = vv[i] + bo;
        }
    }
}

extern "C" void kernel_launch(void* const* d_in, const int* in_sizes, int n_in,
                              void* d_out, int out_size, void* d_ws, size_t ws_size,
                              hipStream_t stream) {
    const float* x    = (const float*)d_in[0];  // (4,64,40962) fp32
    const int*   nidx = (const int*)d_in[1];    // (40962,27) int32
    const float* nwt  = (const float*)d_in[2];  // (40962,27) fp32
    const float* W    = (const float*)d_in[3];  // (64,576) fp32
    const float* bias = (const float*)d_in[4];  // (64,) fp32
    float* out = (float*)d_out;                 // (4,64,40962) fp32

    unsigned short* Wp    = (unsigned short*)d_ws;                       // 72 KB
    unsigned short* xt    = (unsigned short*)((char*)d_ws + 131072);     // 21 MB
    unsigned int*   pairs = (unsigned int*)((char*)d_ws + 131072 + (size_t)NB * NV * NC * 2);  // 4.6 MB

    prep_kernel<<<dim3((NV * NPAD + 255) / 256), 256, 0, stream>>>(W, nidx, nwt, Wp, pairs);
    transpose_kernel<<<dim3((NV + 63) / 64, NB), 256, 0, stream>>>(x, xt);
    fused_kernel<<<dim3((NV + 15) / 16), 256, 0, stream>>>(xt, pairs, Wp, bias, out);
}

// Round 4
// 229.654 us; speedup vs baseline: 1.1758x; 1.1758x over previous
//
#include <hip/hip_runtime.h>
#include <hip/hip_fp16.h>
#include <stdint.h>
#include <string.h>

#define NV 40962     // vertices
#define NC 64        // in channels
#define NO 64        // out channels
#define NM 27        // neighbors*3
#define NB 4         // batch
#define KP 576       // K = 9*64, permuted t = k*64 + c (k-major)
#define NPAD 28      // padded pairs per vertex (112 B rows, 16B-aligned)
#define NT 2561      // vertex tiles = ceil(NV/16)

using fragh = __attribute__((ext_vector_type(8))) _Float16;  // 8 f16 (4 VGPRs)
using f32x4 = __attribute__((ext_vector_type(4))) float;     // MFMA acc

__device__ inline __half2 uh2(unsigned int u) { __half2 h; memcpy(&h, &u, 4); return h; }
__device__ inline unsigned int h2u(__half2 h) { unsigned int u; memcpy(&u, &h, 4); return u; }
__device__ inline unsigned short f2h(float f) {
    __half h = __float2half_rn(f);
    unsigned short u; memcpy(&u, &h, 2); return u;
}
__device__ inline unsigned int pack_h2(float a, float b) {
    __half2 h = __floats2half2_rn(a, b);
    unsigned int u; memcpy(&u, &h, 4); return u;
}
__device__ inline unsigned int comp(const uint4& v, int i) {
    switch (i & 3) { case 0: return v.x; case 1: return v.y; case 2: return v.z; default: return v.w; }
}

// ---- prep: W -> Wp f16 (t = k*64+c), and (idx,w) -> packed pairs (f16 w | idx) ----
__global__ __launch_bounds__(256) void prep_kernel(const float* __restrict__ W,
                                                   const int* __restrict__ nidx,
                                                   const float* __restrict__ nwt,
                                                   unsigned short* __restrict__ Wp,
                                                   unsigned int* __restrict__ pairs) {
    int i = blockIdx.x * 256 + threadIdx.x;
    if (i < NO * KP) {
        int o = i / KP, t = i % KP;
        int k = t >> 6, c = t & 63;
        Wp[i] = f2h(W[o * 576 + c * 9 + k]);
    }
    if (i < NV * NPAD) {
        int v = i / NPAD, j = i - v * NPAD;
        unsigned int pv = 0;
        if (j < NM) {
            unsigned int id = (unsigned int)nidx[v * NM + j];   // < 40962, fits 16 bits
            unsigned int wb = (unsigned int)f2h(nwt[v * NM + j]);
            pv = (wb << 16) | (id & 0xffffu);
        }
        pairs[i] = pv;
    }
}

// ---- x (B,C,V) fp32 -> xt (B,V,C) f16 ----
__global__ __launch_bounds__(256) void transpose_kernel(const float* __restrict__ x,
                                                        unsigned short* __restrict__ xt) {
    __shared__ float tile[64][65];
    int b = blockIdx.y;
    int v0 = blockIdx.x * 64;
    int t = threadIdx.x;
    int tv = t & 63, tc = t >> 6;
    const float* xb = x + (size_t)b * NC * NV;
    #pragma unroll
    for (int i = 0; i < 16; i++) {
        int c = tc + i * 4;
        int v = v0 + tv;
        tile[c][tv] = (v < NV) ? xb[(size_t)c * NV + v] : 0.f;
    }
    __syncthreads();
    unsigned short* xtb = xt + (size_t)b * NV * NC;
    #pragma unroll
    for (int i = 0; i < 2; i++) {
        int r = i * 32 + (t >> 3);
        int ch0 = (t & 7) * 8;
        int v = v0 + r;
        if (v < NV) {
            unsigned int o[4];
            #pragma unroll
            for (int j = 0; j < 4; j++)
                o[j] = pack_h2(tile[ch0 + 2 * j][r], tile[ch0 + 2 * j + 1][r]);
            *(uint4*)(xtb + (size_t)v * NC + ch0) = *(const uint4*)o;
        }
    }
}

// ---- fused gather + MFMA GEMM, zero LDS, per-kslot interleave ----
// block = 64 = 1 wave; wave = 16 vertices x 64 outputs x 2 BATCHES (round-1
// proven structure). lane = (q = lane>>4, m = lane&15).
// XCD affinity: 1D grid, bid%8 = XCD (empirical round-robin); XCDs 0-3 take
// batch pair 0, XCDs 4-7 take pair 1 -> per-XCD gather working set 10.4 MB
// (vs 21 MB interleaved) -> higher L2 hit on the random gathers.
// Triple-buffered gather pipeline (lookahead 2): 24 uint4 in flight in
// source; __launch_bounds__(64,2) leaves 256-VGPR headroom so the register
// allocator can honor the lookahead instead of sinking the loads.
__global__ __launch_bounds__(64, 2) void fused_kernel(
    const unsigned short* __restrict__ xt,
    const unsigned int* __restrict__ pairs,
    const unsigned short* __restrict__ Wp,
    const float* __restrict__ bias,
    float* __restrict__ out)
{
    int lane = threadIdx.x;
    int q = lane >> 4;          // channel quad
    int m = lane & 15;          // vertex within tile

    int bid = blockIdx.x;
    int xcd = bid & 7;
    int bp = xcd >> 2;                         // batch pair 0/1
    int tile = ((bid >> 3) << 2) + (xcd & 3);  // tile index within batch pair
    if (tile >= NT) return;
    int n0 = tile * 16;

    int vtx = n0 + m; if (vtx >= NV) vtx = NV - 1;
    const char* xb0 = (const char*)xt + (size_t)(2 * bp) * NV * NC * 2;
    const char* xb1 = xb0 + (size_t)NV * NC * 2;
    int cofs = q * 16;

    // all 27 (idx | f16 w) pairs for this lane's vertex
    uint4 pr[7];
    {
        const uint4* pp = (const uint4*)(pairs + (size_t)vtx * NPAD);
        #pragma unroll
        for (int j = 0; j < 7; j++) pr[j] = pp[j];
    }

    f32x4 c[2][4];
    #pragma unroll
    for (int bb = 0; bb < 2; bb++)
        #pragma unroll
        for (int j = 0; j < 4; j++) c[bb][j] = (f32x4){0.f, 0.f, 0.f, 0.f};

    uint4 ga[3][2][3], gb[3][2][3];  // [buf][batch][neighbor], triple buffer

    auto issue = [&](int buf, int slot) {
        #pragma unroll
        for (int j = 0; j < 3; j++) {
            int mm = 3 * slot + j;
            unsigned int pm = comp(pr[mm >> 2], mm);
            unsigned int off = ((pm & 0xffffu) << 7) + cofs;
            ga[buf][0][j] = *(const uint4*)(xb0 + off);
            gb[buf][0][j] = *(const uint4*)(xb0 + off + 64);
            ga[buf][1][j] = *(const uint4*)(xb1 + off);
            gb[buf][1][j] = *(const uint4*)(xb1 + off + 64);
        }
    };

    // prologue: issue k-slots 0 and 1
    issue(0, 0);
    issue(1, 1);

    const unsigned short* wrow = Wp + q * 8;

    #pragma unroll
    for (int k = 0; k < 9; k++) {
        int cur = k % 3;
        // lookahead: issue k+2's 12 gathers before consuming k's
        if (k < 7) issue((k + 2) % 3, k + 2);

        // accumulate k's 3 neighbors, 16 channels x 2 batches — packed f16 fma
        unsigned int accA[2][4], accB[2][4];
        #pragma unroll
        for (int bb = 0; bb < 2; bb++)
            #pragma unroll
            for (int d = 0; d < 4; d++) { accA[bb][d] = 0u; accB[bb][d] = 0u; }
        #pragma unroll
        for (int j = 0; j < 3; j++) {
            int mm = 3 * k + j;
            unsigned int pm = comp(pr[mm >> 2], mm);
            unsigned int wh = pm >> 16;
            __half2 w2 = uh2((wh << 16) | wh);
            #pragma unroll
            for (int bb = 0; bb < 2; bb++) {
                uint4 u0 = bb ? ga[cur][1][j] : ga[cur][0][j];
                uint4 u1 = bb ? gb[cur][1][j] : gb[cur][0][j];
                const unsigned int d0[4] = {u0.x, u0.y, u0.z, u0.w};
                const unsigned int d1[4] = {u1.x, u1.y, u1.z, u1.w};
                #pragma unroll
                for (int d = 0; d < 4; d++) {
                    accA[bb][d] = h2u(__hfma2(uh2(d0[d]), w2, uh2(accA[bb][d])));
                    accB[bb][d] = h2u(__hfma2(uh2(d1[d]), w2, uh2(accB[bb][d])));
                }
            }
        }
        // acc registers ARE the A-frags; run k-steps 2k (lo) and 2k+1 (hi)
        fragh a0[2], a1[2];
        #pragma unroll
        for (int bb = 0; bb < 2; bb++) {
            memcpy(&a0[bb], accA[bb], 16);
            memcpy(&a1[bb], accB[bb], 16);
        }
        #pragma unroll
        for (int j = 0; j < 4; j++) {
            fragh blo = *(const fragh*)(wrow + (size_t)(j * 16 + m) * KP + (2 * k) * 32);
            fragh bhi = *(const fragh*)(wrow + (size_t)(j * 16 + m) * KP + (2 * k + 1) * 32);
            c[0][j] = __builtin_amdgcn_mfma_f32_16x16x32_f16(a0[0], blo, c[0][j], 0, 0, 0);
            c[0][j] = __builtin_amdgcn_mfma_f32_16x16x32_f16(a1[0], bhi, c[0][j], 0, 0, 0);
            c[1][j] = __builtin_amdgcn_mfma_f32_16x16x32_f16(a0[1], blo, c[1][j], 0, 0, 0);
            c[1][j] = __builtin_amdgcn_mfma_f32_16x16x32_f16(a1[1], bhi, c[1][j], 0, 0, 0);
        }
    }

    // epilogue: D[row = q*4+i (vertex)][col = m+16j (out)], + bias, float2 stores
    int nbase = n0 + q * 4;
    #pragma unroll
    for (int bb = 0; bb < 2; bb++) {
        size_t outb = (size_t)(2 * bp + bb) * NO * NV;
        #pragma unroll
        for (int j = 0; j < 4; j++) {
            int o = j * 16 + m;
            float bo = bias[o];
            f32x4 vv = c[bb][j];
            float* op = out + outb + (size_t)o * NV + nbase;
            if (nbase + 4 <= NV) {
                *(float2*)op       = make_float2(vv[0] + bo, vv[1] + bo);
                *(float2*)(op + 2) = make_float2(vv[2] + bo, vv[3] + bo);
            } else {
                #pragma unroll
                for (int i = 0; i < 4; i++)
                    if (nbase + i < NV) op[i] = vv[i] + bo;
            }
        }
    }
}

extern "C" void kernel_launch(void* const* d_in, const int* in_sizes, int n_in,
                              void* d_out, int out_size, void* d_ws, size_t ws_size,
                              hipStream_t stream) {
    const float* x    = (const float*)d_in[0];  // (4,64,40962) fp32
    const int*   nidx = (const int*)d_in[1];    // (40962,27) int32
    const float* nwt  = (const float*)d_in[2];  // (40962,27) fp32
    const float* W    = (const float*)d_in[3];  // (64,576) fp32
    const float* bias = (const float*)d_in[4];  // (64,) fp32
    float* out = (float*)d_out;                 // (4,64,40962) fp32

    unsigned short* Wp    = (unsigned short*)d_ws;                       // 72 KB
    unsigned short* xt    = (unsigned short*)((char*)d_ws + 131072);     // 21 MB
    unsigned int*   pairs = (unsigned int*)((char*)d_ws + 131072 + (size_t)NB * NV * NC * 2);  // 4.6 MB

    prep_kernel<<<dim3((NV * NPAD + 255) / 256), 256, 0, stream>>>(W, nidx, nwt, Wp, pairs);
    transpose_kernel<<<dim3((NV + 63) / 64, NB), 256, 0, stream>>>(x, xt);
    // 641*8 = 5128 blocks: (bid>>3) in [0,641), x4 + (bid&3) covers tiles [0,2564) -> guard at 2561
    fused_kernel<<<dim3(5128), 64, 0, stream>>>(xt, pairs, Wp, bias, out);
}

// Round 5
// 225.169 us; speedup vs baseline: 1.1993x; 1.0199x over previous
//
#include <hip/hip_runtime.h>
#include <hip/hip_fp16.h>
#include <stdint.h>
#include <string.h>

#define NV 40962     // vertices
#define NC 64        // in channels
#define NO 64        // out channels
#define NM 27        // neighbors*3
#define NB 4         // batch
#define KP 576       // K = 9*64, permuted t = k*64 + c (k-major)
#define NPAD 28      // padded pairs per vertex (112 B rows, 16B-aligned)
#define NT 2561      // vertex tiles = ceil(NV/16)

using fragh = __attribute__((ext_vector_type(8))) _Float16;  // 8 f16 (4 VGPRs)
using f32x4 = __attribute__((ext_vector_type(4))) float;     // MFMA acc

__device__ inline __half2 uh2(unsigned int u) { __half2 h; memcpy(&h, &u, 4); return h; }
__device__ inline unsigned int h2u(__half2 h) { unsigned int u; memcpy(&u, &h, 4); return u; }
__device__ inline unsigned short f2h(float f) {
    __half h = __float2half_rn(f);
    unsigned short u; memcpy(&u, &h, 2); return u;
}
__device__ inline unsigned int pack_h2(float a, float b) {
    __half2 h = __floats2half2_rn(a, b);
    unsigned int u; memcpy(&u, &h, 4); return u;
}
__device__ inline unsigned int comp(const uint4& v, int i) {
    switch (i & 3) { case 0: return v.x; case 1: return v.y; case 2: return v.z; default: return v.w; }
}

// Inline-asm 16B load: compiler cannot sink it and does NOT track its vmcnt —
// we count manually. volatile preserves issue order between loads.
__device__ __forceinline__ uint4 gload(const void* p) {
    uint4 r;
    asm volatile("global_load_dwordx4 %0, %1, off" : "=v"(r) : "v"(p));
    return r;
}

// ---- prep: W -> Wp f16 (t = k*64+c), and (idx,w) -> packed pairs (f16 w | idx) ----
__global__ __launch_bounds__(256) void prep_kernel(const float* __restrict__ W,
                                                   const int* __restrict__ nidx,
                                                   const float* __restrict__ nwt,
                                                   unsigned short* __restrict__ Wp,
                                                   unsigned int* __restrict__ pairs) {
    int i = blockIdx.x * 256 + threadIdx.x;
    if (i < NO * KP) {
        int o = i / KP, t = i % KP;
        int k = t >> 6, c = t & 63;
        Wp[i] = f2h(W[o * 576 + c * 9 + k]);
    }
    if (i < NV * NPAD) {
        int v = i / NPAD, j = i - v * NPAD;
        unsigned int pv = 0;
        if (j < NM) {
            unsigned int id = (unsigned int)nidx[v * NM + j];   // < 40962, fits 16 bits
            unsigned int wb = (unsigned int)f2h(nwt[v * NM + j]);
            pv = (wb << 16) | (id & 0xffffu);
        }
        pairs[i] = pv;
    }
}

// ---- x (B,C,V) fp32 -> xt (B,V,C) f16 ----
__global__ __launch_bounds__(256) void transpose_kernel(const float* __restrict__ x,
                                                        unsigned short* __restrict__ xt) {
    __shared__ float tile[64][65];
    int b = blockIdx.y;
    int v0 = blockIdx.x * 64;
    int t = threadIdx.x;
    int tv = t & 63, tc = t >> 6;
    const float* xb = x + (size_t)b * NC * NV;
    #pragma unroll
    for (int i = 0; i < 16; i++) {
        int c = tc + i * 4;
        int v = v0 + tv;
        tile[c][tv] = (v < NV) ? xb[(size_t)c * NV + v] : 0.f;
    }
    __syncthreads();
    unsigned short* xtb = xt + (size_t)b * NV * NC;
    #pragma unroll
    for (int i = 0; i < 2; i++) {
        int r = i * 32 + (t >> 3);
        int ch0 = (t & 7) * 8;
        int v = v0 + r;
        if (v < NV) {
            unsigned int o[4];
            #pragma unroll
            for (int j = 0; j < 4; j++)
                o[j] = pack_h2(tile[ch0 + 2 * j][r], tile[ch0 + 2 * j + 1][r]);
            *(uint4*)(xtb + (size_t)v * NC + ch0) = *(const uint4*)o;
        }
    }
}

// ---- fused gather + MFMA GEMM, zero LDS, forced software pipeline ----
// block = 64 = 1 wave; wave = 16 vertices x 64 outputs x 2 BATCHES.
// All k-loop vmem is inline asm with hand-counted s_waitcnt vmcnt(N):
// per iter: issue 8 B-frag loads (k) -> issue 12 gathers (k+1) ->
// vmcnt(20) [gathers k done, 20 newer in flight] -> hfma ->
// vmcnt(12) [bfrags done, k+1 gathers in flight] -> MFMA.
// 12-32 loads stay outstanding per wave CONTINUOUSLY (the compiler-scheduled
// version drains to 0 during compute; VGPR_Count=64 across R1-R4 proved it
// sinks any source-level lookahead). sched_barrier(0) after each wait stops
// consumers hoisting past the wait (rule #18).
__global__ __launch_bounds__(64, 2) void fused_kernel(
    const unsigned short* __restrict__ xt,
    const unsigned int* __restrict__ pairs,
    const unsigned short* __restrict__ Wp,
    const float* __restrict__ bias,
    float* __restrict__ out)
{
    int lane = threadIdx.x;
    int q = lane >> 4;          // channel quad
    int m = lane & 15;          // vertex within tile

    int bid = blockIdx.x;
    int xcd = bid & 7;
    int bp = xcd >> 2;                         // batch pair 0/1
    int tile = ((bid >> 3) << 2) + (xcd & 3);  // tile index within batch pair
    if (tile >= NT) return;
    int n0 = tile * 16;

    int vtx = n0 + m; if (vtx >= NV) vtx = NV - 1;
    const char* xb0 = (const char*)xt + (size_t)(2 * bp) * NV * NC * 2;
    const char* xb1 = xb0 + (size_t)NV * NC * 2;
    int cofs = q * 16;

    // all 27 (idx | f16 w) pairs for this lane's vertex (compiler loads,
    // fully waited before first use -> clean vmcnt slate for the asm pipeline)
    uint4 pr[7];
    {
        const uint4* pp = (const uint4*)(pairs + (size_t)vtx * NPAD);
        #pragma unroll
        for (int j = 0; j < 7; j++) pr[j] = pp[j];
    }

    f32x4 c[2][4];
    #pragma unroll
    for (int bb = 0; bb < 2; bb++)
        #pragma unroll
        for (int j = 0; j < 4; j++) c[bb][j] = (f32x4){0.f, 0.f, 0.f, 0.f};

    // B-frag base pointers: lane reads Wp rows j*16+m, cols q*8.., k-step k
    // at byte offset k*128 (+64 for the odd k-step)
    const char* wb[4];
    #pragma unroll
    for (int j = 0; j < 4; j++)
        wb[j] = (const char*)Wp + (size_t)(j * 16 + m) * KP * 2 + q * 16;

    // gather buffers: [buf][j*4 + batch*2 + half], double-buffered
    uint4 g[2][12];

    auto issue_slot = [&](int buf, int slot) {
        #pragma unroll
        for (int j = 0; j < 3; j++) {
            int mm = 3 * slot + j;
            unsigned int pm = comp(pr[mm >> 2], mm);
            unsigned int off = ((pm & 0xffffu) << 7) + cofs;
            g[buf][j * 4 + 0] = gload(xb0 + off);
            g[buf][j * 4 + 1] = gload(xb0 + off + 64);
            g[buf][j * 4 + 2] = gload(xb1 + off);
            g[buf][j * 4 + 3] = gload(xb1 + off + 64);
        }
    };

    // prologue: slot 0 gathers in flight
    issue_slot(0, 0);

    #pragma unroll
    for (int k = 0; k < 9; k++) {
        int cur = k & 1, nxt = cur ^ 1;

        // 1) issue k's 8 B-frag loads (L2-resident, cheap)
        uint4 bf[8];
        #pragma unroll
        for (int j = 0; j < 4; j++) {
            bf[j * 2]     = gload(wb[j] + k * 128);
            bf[j * 2 + 1] = gload(wb[j] + k * 128 + 64);
        }
        // 2) issue k+1's 12 gathers (stay in flight through k's compute)
        if (k < 8) issue_slot(nxt, k + 1);

        // 3) wait gathers k only (12 k+1 gathers + 8 bfrags remain in flight)
        if (k < 8) { asm volatile("s_waitcnt vmcnt(20)"); }
        else       { asm volatile("s_waitcnt vmcnt(8)");  }
        __builtin_amdgcn_sched_barrier(0);

        // 4) accumulate k's 3 neighbors, 16 channels x 2 batches (packed f16)
        unsigned int accA[2][4], accB[2][4];
        #pragma unroll
        for (int bb = 0; bb < 2; bb++)
            #pragma unroll
            for (int d = 0; d < 4; d++) { accA[bb][d] = 0u; accB[bb][d] = 0u; }
        #pragma unroll
        for (int j = 0; j < 3; j++) {
            int mm = 3 * k + j;
            unsigned int pm = comp(pr[mm >> 2], mm);
            unsigned int wh = pm >> 16;
            __half2 w2 = uh2((wh << 16) | wh);
            #pragma unroll
            for (int bb = 0; bb < 2; bb++) {
                uint4 u0 = g[cur][j * 4 + bb * 2 + 0];   // channels lo
                uint4 u1 = g[cur][j * 4 + bb * 2 + 1];   // channels hi
                const unsigned int d0[4] = {u0.x, u0.y, u0.z, u0.w};
                const unsigned int d1[4] = {u1.x, u1.y, u1.z, u1.w};
                #pragma unroll
                for (int d = 0; d < 4; d++) {
                    accA[bb][d] = h2u(__hfma2(uh2(d0[d]), w2, uh2(accA[bb][d])));
                    accB[bb][d] = h2u(__hfma2(uh2(d1[d]), w2, uh2(accB[bb][d])));
                }
            }
        }

        // 5) wait bfrags (k+1 gathers remain outstanding across the MFMAs)
        if (k < 8) { asm volatile("s_waitcnt vmcnt(12)"); }
        else       { asm volatile("s_waitcnt vmcnt(0)");  }
        __builtin_amdgcn_sched_barrier(0);

        // 6) acc registers ARE the A-frags; k-steps 2k (lo) and 2k+1 (hi)
        fragh a0[2], a1[2];
        #pragma unroll
        for (int bb = 0; bb < 2; bb++) {
            memcpy(&a0[bb], accA[bb], 16);
            memcpy(&a1[bb], accB[bb], 16);
        }
        #pragma unroll
        for (int j = 0; j < 4; j++) {
            fragh blo, bhi;
            memcpy(&blo, &bf[j * 2], 16);
            memcpy(&bhi, &bf[j * 2 + 1], 16);
            c[0][j] = __builtin_amdgcn_mfma_f32_16x16x32_f16(a0[0], blo, c[0][j], 0, 0, 0);
            c[0][j] = __builtin_amdgcn_mfma_f32_16x16x32_f16(a1[0], bhi, c[0][j], 0, 0, 0);
            c[1][j] = __builtin_amdgcn_mfma_f32_16x16x32_f16(a0[1], blo, c[1][j], 0, 0, 0);
            c[1][j] = __builtin_amdgcn_mfma_f32_16x16x32_f16(a1[1], bhi, c[1][j], 0, 0, 0);
        }
    }

    // epilogue: D[row = q*4+i (vertex)][col = m+16j (out)], + bias, float2 stores
    int nbase = n0 + q * 4;
    #pragma unroll
    for (int bb = 0; bb < 2; bb++) {
        size_t outb = (size_t)(2 * bp + bb) * NO * NV;
        #pragma unroll
        for (int j = 0; j < 4; j++) {
            int o = j * 16 + m;
            float bo = bias[o];
            f32x4 vv = c[bb][j];
            float* op = out + outb + (size_t)o * NV + nbase;
            if (nbase + 4 <= NV) {
                *(float2*)op       = make_float2(vv[0] + bo, vv[1] + bo);
                *(float2*)(op + 2) = make_float2(vv[2] + bo, vv[3] + bo);
            } else {
                #pragma unroll
                for (int i = 0; i < 4; i++)
                    if (nbase + i < NV) op[i] = vv[i] + bo;
            }
        }
    }
}

extern "C" void kernel_launch(void* const* d_in, const int* in_sizes, int n_in,
                              void* d_out, int out_size, void* d_ws, size_t ws_size,
                              hipStream_t stream) {
    const float* x    = (const float*)d_in[0];  // (4,64,40962) fp32
    const int*   nidx = (const int*)d_in[1];    // (40962,27) int32
    const float* nwt  = (const float*)d_in[2];  // (40962,27) fp32
    const float* W    = (const float*)d_in[3];  // (64,576) fp32
    const float* bias = (const float*)d_in[4];  // (64,) fp32
    float* out = (float*)d_out;                 // (4,64,40962) fp32

    unsigned short* Wp    = (unsigned short*)d_ws;                       // 72 KB
    unsigned short* xt    = (unsigned short*)((char*)d_ws + 131072);     // 21 MB
    unsigned int*   pairs = (unsigned int*)((char*)d_ws + 131072 + (size_t)NB * NV * NC * 2);  // 4.6 MB

    prep_kernel<<<dim3((NV * NPAD + 255) / 256), 256, 0, stream>>>(W, nidx, nwt, Wp, pairs);
    transpose_kernel<<<dim3((NV + 63) / 64, NB), 256, 0, stream>>>(x, xt);
    // 641*8 = 5128 blocks: (bid>>3) in [0,641), x4 + (bid&3) covers tiles [0,2564) -> guard at 2561
    fused_kernel<<<dim3(5128), 64, 0, stream>>>(xt, pairs, Wp, bias, out);
}

// Round 7
// 222.599 us; speedup vs baseline: 1.2131x; 1.0115x over previous
//
#include <hip/hip_runtime.h>
#include <hip/hip_fp16.h>
#include <stdint.h>
#include <string.h>

#define NV 40962     // vertices
#define NC 64        // in channels
#define NO 64        // out channels
#define NM 27        // neighbors*3
#define NB 4         // batch
#define KP 576       // K = 9*64, permuted t = k*64 + c (k-major)
#define NPAD 28      // padded pairs per vertex (112 B rows, 16B-aligned)
#define NT 2561      // vertex tiles = ceil(NV/16)

using fragh = __attribute__((ext_vector_type(8))) _Float16;  // 8 f16 (4 VGPRs)
using f32x4 = __attribute__((ext_vector_type(4))) float;     // MFMA acc

__device__ inline __half2 uh2(unsigned int u) { __half2 h; memcpy(&h, &u, 4); return h; }
__device__ inline unsigned int h2u(__half2 h) { unsigned int u; memcpy(&u, &h, 4); return u; }
__device__ inline unsigned short f2h(float f) {
    __half h = __float2half_rn(f);
    unsigned short u; memcpy(&u, &h, 2); return u;
}
__device__ inline unsigned int pack_h2(float a, float b) {
    __half2 h = __floats2half2_rn(a, b);
    unsigned int u; memcpy(&u, &h, 4); return u;
}
__device__ inline unsigned int comp(const uint4& v, int i) {
    switch (i & 3) { case 0: return v.x; case 1: return v.y; case 2: return v.z; default: return v.w; }
}

// Inline-asm 16B load: compiler cannot sink it and does NOT track its vmcnt —
// we count manually. volatile preserves issue order between loads.
__device__ __forceinline__ uint4 gload(const void* p) {
    uint4 r;
    asm volatile("global_load_dwordx4 %0, %1, off" : "=v"(r) : "v"(p));
    return r;
}

// ---- prep: W -> Wp f16 (t = k*64+c), and (idx,w) -> packed pairs (f16 w | idx) ----
__global__ __launch_bounds__(256) void prep_kernel(const float* __restrict__ W,
                                                   const int* __restrict__ nidx,
                                                   const float* __restrict__ nwt,
                                                   unsigned short* __restrict__ Wp,
                                                   unsigned int* __restrict__ pairs) {
    int i = blockIdx.x * 256 + threadIdx.x;
    if (i < NO * KP) {
        int o = i / KP, t = i % KP;
        int k = t >> 6, c = t & 63;
        Wp[i] = f2h(W[o * 576 + c * 9 + k]);
    }
    if (i < NV * NPAD) {
        int v = i / NPAD, j = i - v * NPAD;
        unsigned int pv = 0;
        if (j < NM) {
            unsigned int id = (unsigned int)nidx[v * NM + j];   // < 40962, fits 16 bits
            unsigned int wb = (unsigned int)f2h(nwt[v * NM + j]);
            pv = (wb << 16) | (id & 0xffffu);
        }
        pairs[i] = pv;
    }
}

// ---- x (B,C,V) fp32 -> xt (B,V,C) f16 ----
__global__ __launch_bounds__(256) void transpose_kernel(const float* __restrict__ x,
                                                        unsigned short* __restrict__ xt) {
    __shared__ float tile[64][65];
    int b = blockIdx.y;
    int v0 = blockIdx.x * 64;
    int t = threadIdx.x;
    int tv = t & 63, tc = t >> 6;
    const float* xb = x + (size_t)b * NC * NV;
    #pragma unroll
    for (int i = 0; i < 16; i++) {
        int c = tc + i * 4;
        int v = v0 + tv;
        tile[c][tv] = (v < NV) ? xb[(size_t)c * NV + v] : 0.f;
    }
    __syncthreads();
    unsigned short* xtb = xt + (size_t)b * NV * NC;
    #pragma unroll
    for (int i = 0; i < 2; i++) {
        int r = i * 32 + (t >> 3);
        int ch0 = (t & 7) * 8;
        int v = v0 + r;
        if (v < NV) {
            unsigned int o[4];
            #pragma unroll
            for (int j = 0; j < 4; j++)
                o[j] = pack_h2(tile[ch0 + 2 * j][r], tile[ch0 + 2 * j + 1][r]);
            *(uint4*)(xtb + (size_t)v * NC + ch0) = *(const uint4*)o;
        }
    }
}

// ---- fused gather + MFMA GEMM, zero LDS, forced software pipeline ----
// block = 256 = 4 waves; wave w = one 16-vertex tile (grp*4+w), 2 BATCHES.
// Per-wave structure identical to the verified R5 100-VGPR kernel; 4-wave
// packing lifts the single-wave-workgroup residency cap.
// __launch_bounds__(256, 2): VGPR cap 256 — SAME compile regime as R5.
// (R6's (256,4) capped VGPRs at 128 < the pipeline's ~170 live regs ->
// forced spills of asm-load destinations with untracked outstanding loads
// -> UB/crash. Never cap below the pipeline's register footprint.)
// No __syncthreads -> per-wave early-return guard is safe.
// All k-loop vmem is inline asm with hand-counted s_waitcnt vmcnt(N):
// per iter: issue 8 B-frag loads (k) -> issue 12 gathers (k+1) ->
// vmcnt(20) [gathers k done, 20 newer in flight] -> hfma ->
// vmcnt(12) [bfrags done, k+1 gathers in flight] -> MFMA.
__global__ __launch_bounds__(256, 2) void fused_kernel(
    const unsigned short* __restrict__ xt,
    const unsigned int* __restrict__ pairs,
    const unsigned short* __restrict__ Wp,
    const float* __restrict__ bias,
    float* __restrict__ out)
{
    int lane = threadIdx.x & 63;
    int w = threadIdx.x >> 6;   // wave id -> tile within group
    int q = lane >> 4;          // channel quad
    int m = lane & 15;          // vertex within tile

    int bid = blockIdx.x;
    int xcd = bid & 7;
    int bp = xcd >> 2;                         // batch pair 0/1
    int grp = ((bid >> 3) << 2) + (xcd & 3);   // tile-group within batch pair
    int tile = grp * 4 + w;
    if (tile >= NT) return;
    int n0 = tile * 16;

    int vtx = n0 + m; if (vtx >= NV) vtx = NV - 1;
    const char* xb0 = (const char*)xt + (size_t)(2 * bp) * NV * NC * 2;
    const char* xb1 = xb0 + (size_t)NV * NC * 2;
    int cofs = q * 16;

    // all 27 (idx | f16 w) pairs for this lane's vertex (compiler loads,
    // fully waited before first use -> clean vmcnt slate for the asm pipeline)
    uint4 pr[7];
    {
        const uint4* pp = (const uint4*)(pairs + (size_t)vtx * NPAD);
        #pragma unroll
        for (int j = 0; j < 7; j++) pr[j] = pp[j];
    }

    f32x4 c[2][4];
    #pragma unroll
    for (int bb = 0; bb < 2; bb++)
        #pragma unroll
        for (int j = 0; j < 4; j++) c[bb][j] = (f32x4){0.f, 0.f, 0.f, 0.f};

    // B-frag base pointers: lane reads Wp rows j*16+m, cols q*8.., k-step k
    // at byte offset k*128 (+64 for the odd k-step)
    const char* wb[4];
    #pragma unroll
    for (int j = 0; j < 4; j++)
        wb[j] = (const char*)Wp + (size_t)(j * 16 + m) * KP * 2 + q * 16;

    // gather buffers: [buf][j*4 + batch*2 + half], double-buffered
    uint4 g[2][12];

    auto issue_slot = [&](int buf, int slot) {
        #pragma unroll
        for (int j = 0; j < 3; j++) {
            int mm = 3 * slot + j;
            unsigned int pm = comp(pr[mm >> 2], mm);
            unsigned int off = ((pm & 0xffffu) << 7) + cofs;
            g[buf][j * 4 + 0] = gload(xb0 + off);
            g[buf][j * 4 + 1] = gload(xb0 + off + 64);
            g[buf][j * 4 + 2] = gload(xb1 + off);
            g[buf][j * 4 + 3] = gload(xb1 + off + 64);
        }
    };

    // prologue: slot 0 gathers in flight
    issue_slot(0, 0);

    #pragma unroll
    for (int k = 0; k < 9; k++) {
        int cur = k & 1, nxt = cur ^ 1;

        // 1) issue k's 8 B-frag loads (L2-resident, cheap)
        uint4 bf[8];
        #pragma unroll
        for (int j = 0; j < 4; j++) {
            bf[j * 2]     = gload(wb[j] + k * 128);
            bf[j * 2 + 1] = gload(wb[j] + k * 128 + 64);
        }
        // 2) issue k+1's 12 gathers (stay in flight through k's compute)
        if (k < 8) issue_slot(nxt, k + 1);

        // 3) wait gathers k only (12 k+1 gathers + 8 bfrags remain in flight)
        if (k < 8) { asm volatile("s_waitcnt vmcnt(20)"); }
        else       { asm volatile("s_waitcnt vmcnt(8)");  }
        __builtin_amdgcn_sched_barrier(0);

        // 4) accumulate k's 3 neighbors, 16 channels x 2 batches (packed f16)
        unsigned int accA[2][4], accB[2][4];
        #pragma unroll
        for (int bb = 0; bb < 2; bb++)
            #pragma unroll
            for (int d = 0; d < 4; d++) { accA[bb][d] = 0u; accB[bb][d] = 0u; }
        #pragma unroll
        for (int j = 0; j < 3; j++) {
            int mm = 3 * k + j;
            unsigned int pm = comp(pr[mm >> 2], mm);
            unsigned int wh = pm >> 16;
            __half2 w2 = uh2((wh << 16) | wh);
            #pragma unroll
            for (int bb = 0; bb < 2; bb++) {
                uint4 u0 = g[cur][j * 4 + bb * 2 + 0];   // channels lo
                uint4 u1 = g[cur][j * 4 + bb * 2 + 1];   // channels hi
                const unsigned int d0[4] = {u0.x, u0.y, u0.z, u0.w};
                const unsigned int d1[4] = {u1.x, u1.y, u1.z, u1.w};
                #pragma unroll
                for (int d = 0; d < 4; d++) {
                    accA[bb][d] = h2u(__hfma2(uh2(d0[d]), w2, uh2(accA[bb][d])));
                    accB[bb][d] = h2u(__hfma2(uh2(d1[d]), w2, uh2(accB[bb][d])));
                }
            }
        }

        // 5) wait bfrags (k+1 gathers remain outstanding across the MFMAs)
        if (k < 8) { asm volatile("s_waitcnt vmcnt(12)"); }
        else       { asm volatile("s_waitcnt vmcnt(0)");  }
        __builtin_amdgcn_sched_barrier(0);

        // 6) acc registers ARE the A-frags; k-steps 2k (lo) and 2k+1 (hi)
        fragh a0[2], a1[2];
        #pragma unroll
        for (int bb = 0; bb < 2; bb++) {
            memcpy(&a0[bb], accA[bb], 16);
            memcpy(&a1[bb], accB[bb], 16);
        }
        #pragma unroll
        for (int j = 0; j < 4; j++) {
            fragh blo, bhi;
            memcpy(&blo, &bf[j * 2], 16);
            memcpy(&bhi, &bf[j * 2 + 1], 16);
            c[0][j] = __builtin_amdgcn_mfma_f32_16x16x32_f16(a0[0], blo, c[0][j], 0, 0, 0);
            c[0][j] = __builtin_amdgcn_mfma_f32_16x16x32_f16(a1[0], bhi, c[0][j], 0, 0, 0);
            c[1][j] = __builtin_amdgcn_mfma_f32_16x16x32_f16(a0[1], blo, c[1][j], 0, 0, 0);
            c[1][j] = __builtin_amdgcn_mfma_f32_16x16x32_f16(a1[1], bhi, c[1][j], 0, 0, 0);
        }
    }

    // epilogue: D[row = q*4+i (vertex)][col = m+16j (out)], + bias, float2 stores
    int nbase = n0 + q * 4;
    #pragma unroll
    for (int bb = 0; bb < 2; bb++) {
        size_t outb = (size_t)(2 * bp + bb) * NO * NV;
        #pragma unroll
        for (int j = 0; j < 4; j++) {
            int o = j * 16 + m;
            float bo = bias[o];
            f32x4 vv = c[bb][j];
            float* op = out + outb + (size_t)o * NV + nbase;
            if (nbase + 4 <= NV) {
                *(float2*)op       = make_float2(vv[0] + bo, vv[1] + bo);
                *(float2*)(op + 2) = make_float2(vv[2] + bo, vv[3] + bo);
            } else {
                #pragma unroll
                for (int i = 0; i < 4; i++)
                    if (nbase + i < NV) op[i] = vv[i] + bo;
            }
        }
    }
}

extern "C" void kernel_launch(void* const* d_in, const int* in_sizes, int n_in,
                              void* d_out, int out_size, void* d_ws, size_t ws_size,
                              hipStream_t stream) {
    const float* x    = (const float*)d_in[0];  // (4,64,40962) fp32
    const int*   nidx = (const int*)d_in[1];    // (40962,27) int32
    const float* nwt  = (const float*)d_in[2];  // (40962,27) fp32
    const float* W    = (const float*)d_in[3];  // (64,576) fp32
    const float* bias = (const float*)d_in[4];  // (64,) fp32
    float* out = (float*)d_out;                 // (4,64,40962) fp32

    unsigned short* Wp    = (unsigned short*)d_ws;                       // 72 KB
    unsigned short* xt    = (unsigned short*)((char*)d_ws + 131072);     // 21 MB
    unsigned int*   pairs = (unsigned int*)((char*)d_ws + 131072 + (size_t)NB * NV * NC * 2);  // 4.6 MB

    prep_kernel<<<dim3((NV * NPAD + 255) / 256), 256, 0, stream>>>(W, nidx, nwt, Wp, pairs);
    transpose_kernel<<<dim3((NV + 63) / 64, NB), 256, 0, stream>>>(x, xt);
    // 161*8 = 1288 blocks of 4 waves; grp = (bid>>3)*4 + (bid&3) covers
    // tile-groups [0,644) per batch pair; per-wave tile guard at NT=2561
    fused_kernel<<<dim3(1288), 256, 0, stream>>>(xt, pairs, Wp, bias, out);
}